// Round 3
// baseline (758.222 us; speedup 1.0000x reference)
//
#include <hip/hip_runtime.h>
#include <hip/hip_cooperative_groups.h>
#include <math.h>

namespace cg = cooperative_groups;

#define HS 4096
#define NIN 17
#define NSQ ((size_t)HS * (size_t)HS)
#define G 1024                           // cooperative grid: 4 blocks/CU x 256 CU
#define NG4 4194303u                     // (NSQ - 4) / 4 shifted float4 groups

typedef float vfloat4 __attribute__((ext_vector_type(4)));

__device__ __forceinline__ vfloat4 ntload4(const vfloat4* p) {
  return __builtin_nontemporal_load(p);
}
__device__ __forceinline__ void ntstore4(vfloat4* p, vfloat4 v) {
  __builtin_nontemporal_store(v, p);
}
__device__ __forceinline__ vfloat4 shift3(vfloat4 a, vfloat4 b) {
  return __builtin_shufflevector(a, b, 3, 4, 5, 6);
}

struct Params {
  const float *inputs, *hidden, *hebb, *et, *pw;
  const float *i2h_w, *i2h_b, *w_, *alpha, *eta;
  const float *h2o_w, *h2o_b, *h2v_w, *h2v_b;
  float *out_heads, *out_hactiv, *out_hebb, *out_et, *out_pw, *partial;
};

// Single fused kernel. plo/phi select the phase range: cooperative launch
// runs (0,2) with grid.sync() between phases; fallback launches (0,0),(1,1),
// (2,2) as ordinary kernels (kernel boundaries provide the sync + L2 flush).
__global__ __launch_bounds__(256, 4) void fused_k(Params p, int plo, int phi) {
  __shared__ float red[256];
  const int b = blockIdx.x;
  const int tid = threadIdx.x;
  cg::grid_group grid = cg::this_grid();

  // ---------- Phase 0: matvec partials (2 units/block) + et pass-through ----
  if (plo <= 0) {
#pragma unroll
    for (int uu = 0; uu < 2; ++uu) {
      const int u = b + uu * G;
      const int row0 = (u >> 2) * 8;
      const int j4 = (u & 3) * 256 + tid;                // float4 col idx
      const size_t base = (size_t)row0 * (HS / 4) + j4;
      const vfloat4* wp = reinterpret_cast<const vfloat4*>(p.w_) + base;
      const vfloat4* ap = reinterpret_cast<const vfloat4*>(p.alpha) + base;
      const vfloat4* bp = reinterpret_cast<const vfloat4*>(p.hebb) + base;
      vfloat4 acc = (vfloat4)(0.f);
#pragma unroll
      for (int half = 0; half < 2; ++half) {             // 12 loads in flight
        vfloat4 wv[4], av[4], bv[4];
#pragma unroll
        for (int r = 0; r < 4; ++r) {
          const size_t off = (size_t)(half * 4 + r) * (HS / 4);
          wv[r] = ntload4(wp + off);
          av[r] = ntload4(ap + off);
          bv[r] = bp[off];                               // allocating: phase-2 reuse
        }
#pragma unroll
        for (int r = 0; r < 4; ++r) {
          const float h = p.hidden[row0 + half * 4 + r]; // uniform -> s_load
#pragma unroll
          for (int c = 0; c < 4; ++c)
            acc[c] = fmaf(h, fmaf(av[r][c], bv[r][c], wv[r][c]), acc[c]);
        }
      }
      reinterpret_cast<vfloat4*>(p.partial)[(size_t)(u >> 2) * (HS / 4) + j4] = acc;
    }
    const vfloat4* ep = reinterpret_cast<const vfloat4*>(p.et);
    vfloat4* oe = reinterpret_cast<vfloat4*>(p.out_et + 3);
    const unsigned s0 = (unsigned)b * 4096u + tid;
#pragma unroll 4
    for (int i = 0; i < 16; ++i) {
      const unsigned s = s0 + 256u * i;
      if (s < NG4) {
        const vfloat4 a = ntload4(ep + s);
        const vfloat4 bb = ntload4(ep + s + 1);          // overlap: L1 hit
        ntstore4(oe + s, shift3(a, bb));
      }
    }
  }
  if (plo <= 0 && phi >= 1) grid.sync();

  // ---------- Phase 1: finalize (blocks 0..63)  ||  pw copy (64..1023) -----
  if (plo <= 1 && phi >= 1) {
    if (b < 64) {
      const int col = b * 64 + (tid & 63);
      const int g = tid >> 6;                            // 4 chunk groups
      float acc = 0.f;
#pragma unroll 16
      for (int k = 0; k < 128; ++k)
        acc += p.partial[(size_t)(g * 128 + k) * HS + col];
      red[tid] = acc;
      __syncthreads();
      if (tid < 64) {
        float s = red[tid] + red[tid + 64] + red[tid + 128] + red[tid + 192];
#pragma unroll
        for (int l = 0; l < NIN; ++l)
          s = fmaf(p.inputs[l], p.i2h_w[(size_t)col * NIN + l], s);
        p.out_hactiv[col] = tanhf(s + p.i2h_b[col]);
      }
    } else {
      const vfloat4* pp = reinterpret_cast<const vfloat4*>(p.pw);
      vfloat4* op = reinterpret_cast<vfloat4*>(p.out_pw + 3);
      const unsigned lo = (unsigned)(b - 64) * 4370u;
      const unsigned hi0 = lo + 4370u;
      const unsigned hi = (hi0 < NG4) ? hi0 : NG4;
      for (unsigned s = lo + tid; s < hi; s += 256u) {
        const vfloat4 a = ntload4(pp + s);
        const vfloat4 bb = ntload4(pp + s + 1);
        ntstore4(op + s, shift3(a, bb));
      }
    }
  }
  if (plo <= 1 && phi >= 2) grid.sync();

  // ---------- Phase 2: hebb update + heads + scalar patch -------------------
  if (phi >= 2) {
    const float e = p.eta[0], om = 1.f - e;
    if (b < 5) {                                         // output heads
      const int r = b;
      const float* wrow = (r < 4) ? (p.h2o_w + (size_t)r * HS) : p.h2v_w;
      float s = 0.f;
      for (int j = tid; j < HS; j += 256) s = fmaf(p.out_hactiv[j], wrow[j], s);
      red[tid] = s;
      __syncthreads();
      for (int off = 128; off > 0; off >>= 1) {
        if (tid < off) red[tid] += red[tid + off];
        __syncthreads();
      }
      if (tid == 0)
        p.out_heads[r] = red[0] + ((r < 4) ? p.h2o_b[r] : p.h2v_b[0]);
    } else if (b == 5 && tid == 0) {                     // head/tail scalars
      const float f0 = e * p.hidden[0], fl = e * p.hidden[HS - 1];
#pragma unroll
      for (int k = 0; k < 3; ++k) {
        p.out_et[k] = p.et[k];
        p.out_pw[k] = p.pw[k];
        p.out_hebb[k] = fmaf(om, p.hebb[k], f0 * p.out_hactiv[k]);
      }
      p.out_et[NSQ - 1] = p.et[NSQ - 1];
      p.out_pw[NSQ - 1] = p.pw[NSQ - 1];
      p.out_hebb[NSQ - 1] = fmaf(om, p.hebb[NSQ - 1], fl * p.out_hactiv[HS - 1]);
    }
    const vfloat4* hp = reinterpret_cast<const vfloat4*>(p.hebb);
    vfloat4* oh = reinterpret_cast<vfloat4*>(p.out_hebb + 3);
    const unsigned s0 = (unsigned)b * 4096u + tid;
#pragma unroll 4
    for (int i = 0; i < 16; ++i) {
      const unsigned s = s0 + 256u * i;
      if (s < NG4) {
        const vfloat4 hA = hp[s];                        // L2/L3-warm from phase 0
        const vfloat4 hB = hp[s + 1];
        const unsigned rA = s >> 10, rB = (s + 1) >> 10;
        const unsigned cA = (s & 1023u) * 4u, cB = ((s + 1) & 1023u) * 4u;
        const float fA = e * p.hidden[rA], fB = e * p.hidden[rB];
        vfloat4 oA, oB;
#pragma unroll
        for (int c = 0; c < 4; ++c) {
          oA[c] = fmaf(om, hA[c], fA * p.out_hactiv[cA + c]);
          oB[c] = fmaf(om, hB[c], fB * p.out_hactiv[cB + c]);
        }
        ntstore4(oh + s, shift3(oA, oB));
      }
    }
  }
}

extern "C" void kernel_launch(void* const* d_in, const int* in_sizes, int n_in,
                              void* d_out, int out_size, void* d_ws, size_t ws_size,
                              hipStream_t stream) {
  float* out = (float*)d_out;
  float* out_heads  = out;               // activout[4] + valueout[1]
  float* out_hactiv = out + 5;           // [HS]
  float* out_hebb   = out + 5 + HS;      // [HS*HS] (float offset 4101 == 1 mod 4)
  float* out_et     = out_hebb + NSQ;
  float* out_pw     = out_et + NSQ;

  // Partial scratch: 512*4096 floats = 8 MB. Prefer d_ws; else an aligned
  // slice of the hebb output region (read in phase 1, overwritten in phase 2 —
  // barrier/kernel-ordered, safe).
  const size_t need = (size_t)512 * HS * sizeof(float);
  float* partial = (ws_size >= need) ? (float*)d_ws
                                     : (out_hebb + 3 /* 16B-aligned */);

  Params prm;
  prm.inputs = (const float*)d_in[0];
  prm.hidden = (const float*)d_in[1];
  prm.hebb   = (const float*)d_in[2];
  prm.et     = (const float*)d_in[3];
  prm.pw     = (const float*)d_in[4];
  prm.i2h_w  = (const float*)d_in[5];
  prm.i2h_b  = (const float*)d_in[6];
  prm.w_     = (const float*)d_in[7];
  prm.alpha  = (const float*)d_in[8];
  prm.eta    = (const float*)d_in[9];
  prm.h2o_w  = (const float*)d_in[10];
  prm.h2o_b  = (const float*)d_in[11];
  prm.h2v_w  = (const float*)d_in[12];
  prm.h2v_b  = (const float*)d_in[13];
  prm.out_heads  = out_heads;
  prm.out_hactiv = out_hactiv;
  prm.out_hebb   = out_hebb;
  prm.out_et     = out_et;
  prm.out_pw     = out_pw;
  prm.partial    = partial;

  int plo = 0, phi = 2;
  void* args[] = {&prm, &plo, &phi};
  hipError_t rc = hipLaunchCooperativeKernel(
      reinterpret_cast<const void*>(&fused_k), dim3(G), dim3(256), args, 0, stream);
  if (rc != hipSuccess) {
    // Fallback: same kernel, one launch per phase (kernel boundary = sync).
    hipLaunchKernelGGL(fused_k, dim3(G), dim3(256), 0, stream, prm, 0, 0);
    hipLaunchKernelGGL(fused_k, dim3(G), dim3(256), 0, stream, prm, 1, 1);
    hipLaunchKernelGGL(fused_k, dim3(G), dim3(256), 0, stream, prm, 2, 2);
  }
}

// Round 4
// 459.755 us; speedup vs baseline: 1.6492x; 1.6492x over previous
//
#include <hip/hip_runtime.h>
#include <math.h>

#define HS 4096
#define NIN 17
#define ROW_CHUNKS 512
#define ROWS_PER_CHUNK 8                 // HS / ROW_CHUNKS
#define NSQ ((size_t)HS * (size_t)HS)
// Outputs hebb/et/pw sit at float offset == 1 (mod 4) in the concatenated
// output buffer. We store through (out_X + 3) (16B-aligned) as NG4 shifted
// float4 groups; head floats 0..2 and tail float NSQ-1 are patched scalar.
#define NG4 4194303u                     // (NSQ - 4) / 4

typedef float vfloat4 __attribute__((ext_vector_type(4)));

__device__ __forceinline__ vfloat4 ntload4(const vfloat4* p) {
  return __builtin_nontemporal_load(p);
}
// A/B vs round 2: stores are PLAIN (allocating) — the only kernel on this
// chip measured at 6.7 TB/s (fillBuffer) uses plain dwordx4 stores; every
// nt-store kernel measured 1.0-2.7 TB/s.
__device__ __forceinline__ void store4(vfloat4* p, vfloat4 v) { *p = v; }
// Shifted group j of dst = {srcA.w, srcB.xyz}, srcA = group j, srcB = j+1.
__device__ __forceinline__ vfloat4 shift3(vfloat4 a, vfloat4 b) {
  return __builtin_shufflevector(a, b, 3, 4, 5, 6);
}

// Kernel 1: matvec partials of hidden @ (w + alpha*hebb), fused with the et
// pass-through. grid (4,512)x256. w/alpha/et single-use -> nt loads; hebb is
// re-read by kernel 3 -> allocating load (stays L2/L3-resident).
__global__ __launch_bounds__(256) void matvec_et_k(
    const float* __restrict__ hidden, const float* __restrict__ w,
    const float* __restrict__ alpha, const float* __restrict__ hebb,
    const float* __restrict__ et, float* __restrict__ out_et3,  // out_et+3, 16B-aligned
    float* __restrict__ partial) {
  const int tid = threadIdx.x;
  const int j4 = blockIdx.x * 256 + tid;                 // float4 col, 0..1023
  const int row0 = blockIdx.y * ROWS_PER_CHUNK;
  const size_t base = (size_t)row0 * (HS / 4) + j4;
  const vfloat4* wp = reinterpret_cast<const vfloat4*>(w) + base;
  const vfloat4* ap = reinterpret_cast<const vfloat4*>(alpha) + base;
  const vfloat4* bp = reinterpret_cast<const vfloat4*>(hebb) + base;
  const vfloat4* ep = reinterpret_cast<const vfloat4*>(et);
  vfloat4* oe = reinterpret_cast<vfloat4*>(out_et3);

  // Matvec loads first: 24 independent 16B loads in flight.
  vfloat4 wv[ROWS_PER_CHUNK], av[ROWS_PER_CHUNK], bv[ROWS_PER_CHUNK];
#pragma unroll
  for (int r = 0; r < ROWS_PER_CHUNK; ++r) {
    wv[r] = ntload4(wp + (size_t)r * (HS / 4));
    av[r] = ntload4(ap + (size_t)r * (HS / 4));
    bv[r] = bp[(size_t)r * (HS / 4)];
  }

  // et copy: 8 batches, lane-contiguous shifted groups (coalesced).
  const unsigned s0 = (blockIdx.y * 4u + blockIdx.x) * 2048u + tid;
#pragma unroll
  for (int m = 0; m < 8; ++m) {
    const unsigned s = s0 + 256u * m;
    const unsigned sc = (s < NG4) ? s : (NG4 - 1u);      // clamp single OOB slot
    const vfloat4 a = ntload4(ep + sc);
    const vfloat4 b = ntload4(ep + sc + 1);              // overlap: L1 hit
    if (s < NG4) store4(oe + s, shift3(a, b));
  }

  vfloat4 acc = (vfloat4)(0.f);
#pragma unroll
  for (int r = 0; r < ROWS_PER_CHUNK; ++r) {
    const float h = hidden[row0 + r];                    // block-uniform -> s_load
#pragma unroll
    for (int c = 0; c < 4; ++c)
      acc[c] = fmaf(h, fmaf(av[r][c], bv[r][c], wv[r][c]), acc[c]);
  }
  reinterpret_cast<vfloat4*>(partial)[(size_t)blockIdx.y * (HS / 4) + j4] = acc;
}

// Kernel 2: coalesced reduction of 512 partials + i2h + bias + tanh.
__global__ __launch_bounds__(256) void finalize_k(
    const float* __restrict__ partial, const float* __restrict__ inputs,
    const float* __restrict__ i2h_w, const float* __restrict__ i2h_b,
    float* __restrict__ out_hactiv) {
  const int t = threadIdx.x;
  const int col = blockIdx.x * 64 + (t & 63);
  const int g = t >> 6;                                  // 4 chunk groups
  float acc = 0.f;
#pragma unroll 16
  for (int k = 0; k < ROW_CHUNKS / 4; ++k)
    acc += partial[(size_t)(g * (ROW_CHUNKS / 4) + k) * HS + col];

  __shared__ float red[256];
  red[t] = acc;
  __syncthreads();
  if (t < 64) {
    float s = red[t] + red[t + 64] + red[t + 128] + red[t + 192];
#pragma unroll
    for (int l = 0; l < NIN; ++l)
      s = fmaf(inputs[l], i2h_w[(size_t)col * NIN + l], s);
    out_hactiv[col] = tanhf(s + i2h_b[col]);
  }
}

// Kernel 3: hebb update + pw pass-through, heads + scalar patch in spare
// blocks. Blocks 0..2047: streaming; 2048..2052: heads; 2053: patch.
__global__ __launch_bounds__(256) void hebb_pw_heads_k(
    const float* __restrict__ hebb, const float* __restrict__ hidden,
    const float* __restrict__ hactiv, const float* __restrict__ eta,
    const float* __restrict__ pw, const float* __restrict__ et,
    float* __restrict__ out_hebb, float* __restrict__ out_et,
    float* __restrict__ out_pw,
    const float* __restrict__ h2o_w, const float* __restrict__ h2o_b,
    const float* __restrict__ h2v_w, const float* __restrict__ h2v_b,
    float* __restrict__ out_heads) {
  const int b = blockIdx.x;
  if (b >= 2048) {
    if (b < 2053) {                                      // heads: row b-2048
      const int r = b - 2048;
      const float* wrow = (r < 4) ? (h2o_w + (size_t)r * HS) : h2v_w;
      float s = 0.f;
      for (int j = threadIdx.x; j < HS; j += 256) s = fmaf(hactiv[j], wrow[j], s);
      __shared__ float red[256];
      red[threadIdx.x] = s;
      __syncthreads();
      for (int off = 128; off > 0; off >>= 1) {
        if (threadIdx.x < off) red[threadIdx.x] += red[threadIdx.x + off];
        __syncthreads();
      }
      if (threadIdx.x == 0) out_heads[r] = red[0] + ((r < 4) ? h2o_b[r] : h2v_b[0]);
    } else if (threadIdx.x == 0) {                       // head/tail scalar patch
      const float e = eta[0], om = 1.f - e;
      const float f0 = e * hidden[0], fl = e * hidden[HS - 1];
#pragma unroll
      for (int k = 0; k < 3; ++k) {
        out_et[k] = et[k];
        out_pw[k] = pw[k];
        out_hebb[k] = fmaf(om, hebb[k], f0 * hactiv[k]);
      }
      out_et[NSQ - 1] = et[NSQ - 1];
      out_pw[NSQ - 1] = pw[NSQ - 1];
      out_hebb[NSQ - 1] = fmaf(om, hebb[NSQ - 1], fl * hactiv[HS - 1]);
    }
    return;
  }

  const float e = eta[0], om = 1.f - e;
  const vfloat4* hebbp = reinterpret_cast<const vfloat4*>(hebb);
  const vfloat4* pwp = reinterpret_cast<const vfloat4*>(pw);
  vfloat4* oheb = reinterpret_cast<vfloat4*>(out_hebb + 3);   // 16B-aligned
  vfloat4* opw = reinterpret_cast<vfloat4*>(out_pw + 3);      // 16B-aligned
  const unsigned s0 = b * 2048u + threadIdx.x;
#pragma unroll
  for (int m = 0; m < 8; ++m) {
    const unsigned s = s0 + 256u * m;
    const unsigned sc = (s < NG4) ? s : (NG4 - 1u);
    const vfloat4 pA = ntload4(pwp + sc);
    const vfloat4 pB = ntload4(pwp + sc + 1);
    // hebb update on ALIGNED groups (groups never cross rows: 1024/row),
    // then shifted for the aligned store.
    const vfloat4 hA = hebbp[sc];                        // L2/L3-warm from k1
    const vfloat4 hB = hebbp[sc + 1];
    const unsigned rA = sc >> 10, rB = (sc + 1) >> 10;
    const unsigned cA = (sc & 1023u) * 4u, cB = ((sc + 1) & 1023u) * 4u;
    const float fA = e * hidden[rA], fB = e * hidden[rB];
    vfloat4 oA, oB;
#pragma unroll
    for (int c = 0; c < 4; ++c) {
      oA[c] = fmaf(om, hA[c], fA * hactiv[cA + c]);
      oB[c] = fmaf(om, hB[c], fB * hactiv[cB + c]);
    }
    if (s < NG4) {
      store4(opw + s, shift3(pA, pB));
      store4(oheb + s, shift3(oA, oB));
    }
  }
}

extern "C" void kernel_launch(void* const* d_in, const int* in_sizes, int n_in,
                              void* d_out, int out_size, void* d_ws, size_t ws_size,
                              hipStream_t stream) {
  const float* inputs = (const float*)d_in[0];
  const float* hidden = (const float*)d_in[1];
  const float* hebb   = (const float*)d_in[2];
  const float* et     = (const float*)d_in[3];
  const float* pw     = (const float*)d_in[4];
  const float* i2h_w  = (const float*)d_in[5];
  const float* i2h_b  = (const float*)d_in[6];
  const float* w      = (const float*)d_in[7];
  const float* alpha  = (const float*)d_in[8];
  const float* eta    = (const float*)d_in[9];
  const float* h2o_w  = (const float*)d_in[10];
  const float* h2o_b  = (const float*)d_in[11];
  const float* h2v_w  = (const float*)d_in[12];
  const float* h2v_b  = (const float*)d_in[13];

  float* out = (float*)d_out;
  float* out_heads  = out;               // activout[4] + valueout[1]
  float* out_hactiv = out + 5;           // [HS]
  float* out_hebb   = out + 5 + HS;      // [HS*HS] (float offset 4101 == 1 mod 4)
  float* out_et     = out_hebb + NSQ;
  float* out_pw     = out_et + NSQ;

  // Partial scratch: 512*4096 floats = 8 MB. Prefer d_ws; else an aligned
  // slice of the hebb output region (consumed by finalize_k before
  // hebb_pw_heads_k overwrites it — stream-ordered, safe).
  const size_t need = (size_t)ROW_CHUNKS * HS * sizeof(float);
  float* partial = (ws_size >= need) ? (float*)d_ws
                                     : (out_hebb + 3 /* 16B-aligned */);

  hipLaunchKernelGGL(matvec_et_k, dim3(4, ROW_CHUNKS), dim3(256), 0, stream,
                     hidden, w, alpha, hebb, et, out_et + 3, partial);
  hipLaunchKernelGGL(finalize_k, dim3(HS / 64), dim3(256), 0, stream,
                     partial, inputs, i2h_w, i2h_b, out_hactiv);
  hipLaunchKernelGGL(hebb_pw_heads_k, dim3(2054), dim3(256), 0, stream,
                     hebb, hidden, out_hactiv, eta, pw, et,
                     out_hebb, out_et, out_pw,
                     h2o_w, h2o_b, h2v_w, h2v_b, out_heads);
}

// Round 5
// 458.639 us; speedup vs baseline: 1.6532x; 1.0024x over previous
//
#include <hip/hip_runtime.h>
#include <math.h>

#define HS 4096
#define NIN 17
#define ROW_CHUNKS 512
#define ROWS_PER_CHUNK 8                 // HS / ROW_CHUNKS
#define NSQ ((size_t)HS * (size_t)HS)
// Outputs hebb/et/pw sit at float offset == 1 (mod 4) in the concatenated
// output buffer. We store through (out_X + 3) (16B-aligned) as NG4 shifted
// float4 groups; head floats 0..2 and tail float NSQ-1 are patched scalar.
#define NG4 4194303u                     // (NSQ - 4) / 4

typedef float vfloat4 __attribute__((ext_vector_type(4)));

__device__ __forceinline__ vfloat4 ntload4(const vfloat4* p) {
  return __builtin_nontemporal_load(p);
}
__device__ __forceinline__ void ntstore4(vfloat4* p, vfloat4 v) {
  __builtin_nontemporal_store(v, p);
}
// Shifted group j of dst = {srcA.w, srcB.xyz}, srcA = group j, srcB = j+1.
__device__ __forceinline__ vfloat4 shift3(vfloat4 a, vfloat4 b) {
  return __builtin_shufflevector(a, b, 3, 4, 5, 6);
}

// Kernel 1: PURE matvec partials of hidden @ (w + alpha*hebb). grid (4,512).
// 24 independent 16B loads hoisted in flight; no competing store stream
// (et copy moved to k2). w/alpha single-use -> nt; hebb re-read by k3 ->
// allocating load (stays L2/L3-resident).
__global__ __launch_bounds__(256) void matvec_k(
    const float* __restrict__ hidden, const float* __restrict__ w,
    const float* __restrict__ alpha, const float* __restrict__ hebb,
    float* __restrict__ partial) {
  const int tid = threadIdx.x;
  const int j4 = blockIdx.x * 256 + tid;                 // float4 col, 0..1023
  const int row0 = blockIdx.y * ROWS_PER_CHUNK;
  const size_t base = (size_t)row0 * (HS / 4) + j4;
  const vfloat4* wp = reinterpret_cast<const vfloat4*>(w) + base;
  const vfloat4* ap = reinterpret_cast<const vfloat4*>(alpha) + base;
  const vfloat4* bp = reinterpret_cast<const vfloat4*>(hebb) + base;

  vfloat4 wv[ROWS_PER_CHUNK], av[ROWS_PER_CHUNK], bv[ROWS_PER_CHUNK];
#pragma unroll
  for (int r = 0; r < ROWS_PER_CHUNK; ++r) {
    wv[r] = ntload4(wp + (size_t)r * (HS / 4));
    av[r] = ntload4(ap + (size_t)r * (HS / 4));
    bv[r] = bp[(size_t)r * (HS / 4)];
  }

  vfloat4 acc = (vfloat4)(0.f);
#pragma unroll
  for (int r = 0; r < ROWS_PER_CHUNK; ++r) {
    const float h = hidden[row0 + r];                    // block-uniform -> s_load
#pragma unroll
    for (int c = 0; c < 4; ++c)
      acc[c] = fmaf(h, fmaf(av[r][c], bv[r][c], wv[r][c]), acc[c]);
  }
  reinterpret_cast<vfloat4*>(partial)[(size_t)blockIdx.y * (HS / 4) + j4] = acc;
}

// Kernel 2: finalize (blocks 0..63) in parallel with the et pass-through
// (blocks 64..1087). The copy fills the BW that the tiny latency-bound
// finalize phase would otherwise leave idle.
__global__ __launch_bounds__(256) void finalize_et_k(
    const float* __restrict__ partial, const float* __restrict__ inputs,
    const float* __restrict__ i2h_w, const float* __restrict__ i2h_b,
    const float* __restrict__ et, float* __restrict__ out_et3,  // out_et+3
    float* __restrict__ out_hactiv) {
  const int b = blockIdx.x;
  const int t = threadIdx.x;
  if (b < 64) {
    const int col = b * 64 + (t & 63);
    const int g = t >> 6;                                // 4 chunk groups
    float acc = 0.f;
#pragma unroll 16
    for (int k = 0; k < ROW_CHUNKS / 4; ++k)
      acc += partial[(size_t)(g * (ROW_CHUNKS / 4) + k) * HS + col];
    __shared__ float red[256];
    red[t] = acc;
    __syncthreads();
    if (t < 64) {
      float s = red[t] + red[t + 64] + red[t + 128] + red[t + 192];
#pragma unroll
      for (int l = 0; l < NIN; ++l)
        s = fmaf(inputs[l], i2h_w[(size_t)col * NIN + l], s);
      out_hactiv[col] = tanhf(s + i2h_b[col]);
    }
  } else {
    const vfloat4* ep = reinterpret_cast<const vfloat4*>(et);
    vfloat4* oe = reinterpret_cast<vfloat4*>(out_et3);
    const unsigned s0 = (unsigned)(b - 64) * 4096u + t;  // 1024 copy blocks
#pragma unroll 4
    for (int i = 0; i < 16; ++i) {
      const unsigned s = s0 + 256u * i;
      if (s < NG4) {
        const vfloat4 a = ntload4(ep + s);
        const vfloat4 bb = ntload4(ep + s + 1);          // overlap: L1 hit
        ntstore4(oe + s, shift3(a, bb));
      }
    }
  }
}

// Kernel 3: hebb update + pw pass-through, heads + scalar patch in spare
// blocks. Blocks 0..2047: streaming; 2048..2052: heads; 2053: patch.
// (Identical to the 451.26 µs round-2 version — nt stores kept.)
__global__ __launch_bounds__(256) void hebb_pw_heads_k(
    const float* __restrict__ hebb, const float* __restrict__ hidden,
    const float* __restrict__ hactiv, const float* __restrict__ eta,
    const float* __restrict__ pw, const float* __restrict__ et,
    float* __restrict__ out_hebb, float* __restrict__ out_et,
    float* __restrict__ out_pw,
    const float* __restrict__ h2o_w, const float* __restrict__ h2o_b,
    const float* __restrict__ h2v_w, const float* __restrict__ h2v_b,
    float* __restrict__ out_heads) {
  const int b = blockIdx.x;
  if (b >= 2048) {
    if (b < 2053) {                                      // heads: row b-2048
      const int r = b - 2048;
      const float* wrow = (r < 4) ? (h2o_w + (size_t)r * HS) : h2v_w;
      float s = 0.f;
      for (int j = threadIdx.x; j < HS; j += 256) s = fmaf(hactiv[j], wrow[j], s);
      __shared__ float red[256];
      red[threadIdx.x] = s;
      __syncthreads();
      for (int off = 128; off > 0; off >>= 1) {
        if (threadIdx.x < off) red[threadIdx.x] += red[threadIdx.x + off];
        __syncthreads();
      }
      if (threadIdx.x == 0) out_heads[r] = red[0] + ((r < 4) ? h2o_b[r] : h2v_b[0]);
    } else if (threadIdx.x == 0) {                       // head/tail scalar patch
      const float e = eta[0], om = 1.f - e;
      const float f0 = e * hidden[0], fl = e * hidden[HS - 1];
#pragma unroll
      for (int k = 0; k < 3; ++k) {
        out_et[k] = et[k];
        out_pw[k] = pw[k];
        out_hebb[k] = fmaf(om, hebb[k], f0 * hactiv[k]);
      }
      out_et[NSQ - 1] = et[NSQ - 1];
      out_pw[NSQ - 1] = pw[NSQ - 1];
      out_hebb[NSQ - 1] = fmaf(om, hebb[NSQ - 1], fl * hactiv[HS - 1]);
    }
    return;
  }

  const float e = eta[0], om = 1.f - e;
  const vfloat4* hebbp = reinterpret_cast<const vfloat4*>(hebb);
  const vfloat4* pwp = reinterpret_cast<const vfloat4*>(pw);
  vfloat4* oheb = reinterpret_cast<vfloat4*>(out_hebb + 3);   // 16B-aligned
  vfloat4* opw = reinterpret_cast<vfloat4*>(out_pw + 3);      // 16B-aligned
  const unsigned s0 = b * 2048u + threadIdx.x;
#pragma unroll
  for (int m = 0; m < 8; ++m) {
    const unsigned s = s0 + 256u * m;
    const unsigned sc = (s < NG4) ? s : (NG4 - 1u);
    const vfloat4 pA = ntload4(pwp + sc);
    const vfloat4 pB = ntload4(pwp + sc + 1);
    // hebb update on ALIGNED groups (groups never cross rows: 1024/row),
    // then shifted for the aligned store.
    const vfloat4 hA = hebbp[sc];                        // L2/L3-warm from k1
    const vfloat4 hB = hebbp[sc + 1];
    const unsigned rA = sc >> 10, rB = (sc + 1) >> 10;
    const unsigned cA = (sc & 1023u) * 4u, cB = ((sc + 1) & 1023u) * 4u;
    const float fA = e * hidden[rA], fB = e * hidden[rB];
    vfloat4 oA, oB;
#pragma unroll
    for (int c = 0; c < 4; ++c) {
      oA[c] = fmaf(om, hA[c], fA * hactiv[cA + c]);
      oB[c] = fmaf(om, hB[c], fB * hactiv[cB + c]);
    }
    if (s < NG4) {
      ntstore4(opw + s, shift3(pA, pB));
      ntstore4(oheb + s, shift3(oA, oB));
    }
  }
}

extern "C" void kernel_launch(void* const* d_in, const int* in_sizes, int n_in,
                              void* d_out, int out_size, void* d_ws, size_t ws_size,
                              hipStream_t stream) {
  const float* inputs = (const float*)d_in[0];
  const float* hidden = (const float*)d_in[1];
  const float* hebb   = (const float*)d_in[2];
  const float* et     = (const float*)d_in[3];
  const float* pw     = (const float*)d_in[4];
  const float* i2h_w  = (const float*)d_in[5];
  const float* i2h_b  = (const float*)d_in[6];
  const float* w      = (const float*)d_in[7];
  const float* alpha  = (const float*)d_in[8];
  const float* eta    = (const float*)d_in[9];
  const float* h2o_w  = (const float*)d_in[10];
  const float* h2o_b  = (const float*)d_in[11];
  const float* h2v_w  = (const float*)d_in[12];
  const float* h2v_b  = (const float*)d_in[13];

  float* out = (float*)d_out;
  float* out_heads  = out;               // activout[4] + valueout[1]
  float* out_hactiv = out + 5;           // [HS]
  float* out_hebb   = out + 5 + HS;      // [HS*HS] (float offset 4101 == 1 mod 4)
  float* out_et     = out_hebb + NSQ;
  float* out_pw     = out_et + NSQ;

  // Partial scratch: 512*4096 floats = 8 MB. Prefer d_ws; else an aligned
  // slice of the hebb output region (consumed by finalize_et_k before
  // hebb_pw_heads_k overwrites it — stream-ordered, safe).
  const size_t need = (size_t)ROW_CHUNKS * HS * sizeof(float);
  float* partial = (ws_size >= need) ? (float*)d_ws
                                     : (out_hebb + 3 /* 16B-aligned */);

  hipLaunchKernelGGL(matvec_k, dim3(4, ROW_CHUNKS), dim3(256), 0, stream,
                     hidden, w, alpha, hebb, partial);
  hipLaunchKernelGGL(finalize_et_k, dim3(64 + 1024), dim3(256), 0, stream,
                     partial, inputs, i2h_w, i2h_b, et, out_et + 3, out_hactiv);
  hipLaunchKernelGGL(hebb_pw_heads_k, dim3(2054), dim3(256), 0, stream,
                     hebb, hidden, out_hactiv, eta, pw, et,
                     out_hebb, out_et, out_pw,
                     h2o_w, h2o_b, h2v_w, h2v_b, out_heads);
}

// Round 8
// 455.158 us; speedup vs baseline: 1.6658x; 1.0076x over previous
//
#include <hip/hip_runtime.h>
#include <math.h>

// Plastic-RNN single step (best-measured config, R2 lineage: 451.3/451.8 us).
// Resubmission with refreshed source text to rule out a poisoned build cache;
// semantics identical to the R2/R6 kernel.

#define HS 4096
#define NIN 17
#define ROW_CHUNKS 512
#define RPC 8                            // rows per chunk = HS / ROW_CHUNKS
#define NSQ ((size_t)HS * (size_t)HS)
// hebb/et/pw outputs live at float offset == 1 (mod 4) in the concatenated
// output buffer. Stores go through (out_X + 3), which IS 16B-aligned, as NG4
// shifted float4 groups: group j covers floats [3+4j, 6+4j]. Head floats
// 0..2 and the tail float NSQ-1 are patched by a dedicated block.
#define NG4 4194303u                     // (NSQ - 4) / 4

typedef float vf4 __attribute__((ext_vector_type(4)));

__device__ __forceinline__ vf4 ld_nt(const vf4* p) {
  return __builtin_nontemporal_load(p);
}
__device__ __forceinline__ void st_nt(vf4* p, vf4 v) {
  __builtin_nontemporal_store(v, p);
}
// Shifted group j of dst = {a.w, b.xyz} with a = src group j, b = group j+1.
__device__ __forceinline__ vf4 sh3(vf4 a, vf4 b) {
  return __builtin_shufflevector(a, b, 3, 4, 5, 6);
}

// K1: matvec partials of hidden @ (w + alpha*hebb) fused with the et copy.
// grid (4,512)x256. w/alpha/et single-use -> nt loads; hebb re-read by K3 ->
// allocating load (stays L2/L3-resident).
__global__ __launch_bounds__(256) void matvec_et_k(
    const float* __restrict__ hidden, const float* __restrict__ w,
    const float* __restrict__ alpha, const float* __restrict__ hebb,
    const float* __restrict__ et, float* __restrict__ out_et3,
    float* __restrict__ partial) {
  const int tid = threadIdx.x;
  const int j4 = blockIdx.x * 256 + tid;                 // float4 col, 0..1023
  const int row0 = blockIdx.y * RPC;
  const size_t base = (size_t)row0 * (HS / 4) + j4;
  const vf4* wp = reinterpret_cast<const vf4*>(w) + base;
  const vf4* ap = reinterpret_cast<const vf4*>(alpha) + base;
  const vf4* bp = reinterpret_cast<const vf4*>(hebb) + base;
  const vf4* ep = reinterpret_cast<const vf4*>(et);
  vf4* oe = reinterpret_cast<vf4*>(out_et3);

  // 24 independent 16B loads hoisted up front (MLP >> latency-BW product).
  vf4 wv[RPC], av[RPC], bv[RPC];
#pragma unroll
  for (int r = 0; r < RPC; ++r) {
    wv[r] = ld_nt(wp + (size_t)r * (HS / 4));
    av[r] = ld_nt(ap + (size_t)r * (HS / 4));
    bv[r] = bp[(size_t)r * (HS / 4)];
  }

  // et copy: 8 lane-contiguous shifted-group batches (coalesced both sides).
  const unsigned s0 = (blockIdx.y * 4u + blockIdx.x) * 2048u + tid;
#pragma unroll
  for (int m = 0; m < 8; ++m) {
    const unsigned s = s0 + 256u * m;
    const unsigned sc = (s < NG4) ? s : (NG4 - 1u);      // clamp lone OOB slot
    const vf4 a = ld_nt(ep + sc);
    const vf4 b = ld_nt(ep + sc + 1);                    // overlap: L1 hit
    if (s < NG4) st_nt(oe + s, sh3(a, b));
  }

  vf4 acc = (vf4)(0.f);
#pragma unroll
  for (int r = 0; r < RPC; ++r) {
    const float h = hidden[row0 + r];                    // block-uniform
#pragma unroll
    for (int c = 0; c < 4; ++c)
      acc[c] = fmaf(h, fmaf(av[r][c], bv[r][c], wv[r][c]), acc[c]);
  }
  reinterpret_cast<vf4*>(partial)[(size_t)blockIdx.y * (HS / 4) + j4] = acc;
}

// K2: coalesced reduction of 512 partials + i2h + bias + tanh.
__global__ __launch_bounds__(256) void finalize_k(
    const float* __restrict__ partial, const float* __restrict__ inputs,
    const float* __restrict__ i2h_w, const float* __restrict__ i2h_b,
    float* __restrict__ out_hactiv) {
  const int t = threadIdx.x;
  const int col = blockIdx.x * 64 + (t & 63);
  const int g = t >> 6;                                  // 4 chunk groups
  float acc = 0.f;
#pragma unroll 16
  for (int k = 0; k < ROW_CHUNKS / 4; ++k)
    acc += partial[(size_t)(g * (ROW_CHUNKS / 4) + k) * HS + col];

  __shared__ float red[256];
  red[t] = acc;
  __syncthreads();
  if (t < 64) {
    float s = red[t] + red[t + 64] + red[t + 128] + red[t + 192];
#pragma unroll
    for (int l = 0; l < NIN; ++l)
      s = fmaf(inputs[l], i2h_w[(size_t)col * NIN + l], s);
    out_hactiv[col] = tanhf(s + i2h_b[col]);
  }
}

// K3: hebb update + pw copy (aligned dwordx4 streams) with the 5 output heads
// and the per-array head/tail scalars folded into spare blocks.
// Blocks 0..2047: streaming; 2048..2052: heads; 2053: scalar patch.
__global__ __launch_bounds__(256) void hebb_pw_heads_k(
    const float* __restrict__ hebb, const float* __restrict__ hidden,
    const float* __restrict__ hactiv, const float* __restrict__ eta,
    const float* __restrict__ pw, const float* __restrict__ et,
    float* __restrict__ out_hebb, float* __restrict__ out_et,
    float* __restrict__ out_pw,
    const float* __restrict__ h2o_w, const float* __restrict__ h2o_b,
    const float* __restrict__ h2v_w, const float* __restrict__ h2v_b,
    float* __restrict__ out_heads) {
  const int b = blockIdx.x;
  if (b >= 2048) {
    if (b < 2053) {                                      // head row b-2048
      const int r = b - 2048;
      const float* wrow = (r < 4) ? (h2o_w + (size_t)r * HS) : h2v_w;
      float s = 0.f;
      for (int j = threadIdx.x; j < HS; j += 256) s = fmaf(hactiv[j], wrow[j], s);
      __shared__ float red[256];
      red[threadIdx.x] = s;
      __syncthreads();
      for (int off = 128; off > 0; off >>= 1) {
        if (threadIdx.x < off) red[threadIdx.x] += red[threadIdx.x + off];
        __syncthreads();
      }
      if (threadIdx.x == 0) out_heads[r] = red[0] + ((r < 4) ? h2o_b[r] : h2v_b[0]);
    } else if (threadIdx.x == 0) {                       // scalar patch block
      const float e = eta[0], om = 1.f - e;
      const float f0 = e * hidden[0], fl = e * hidden[HS - 1];
#pragma unroll
      for (int k = 0; k < 3; ++k) {
        out_et[k] = et[k];
        out_pw[k] = pw[k];
        out_hebb[k] = fmaf(om, hebb[k], f0 * hactiv[k]);
      }
      out_et[NSQ - 1] = et[NSQ - 1];
      out_pw[NSQ - 1] = pw[NSQ - 1];
      out_hebb[NSQ - 1] = fmaf(om, hebb[NSQ - 1], fl * hactiv[HS - 1]);
    }
    return;
  }

  const float e = eta[0], om = 1.f - e;
  const vf4* hebbp = reinterpret_cast<const vf4*>(hebb);
  const vf4* pwp = reinterpret_cast<const vf4*>(pw);
  vf4* oheb = reinterpret_cast<vf4*>(out_hebb + 3);      // 16B-aligned
  vf4* opw = reinterpret_cast<vf4*>(out_pw + 3);         // 16B-aligned
  const unsigned s0 = b * 2048u + threadIdx.x;
#pragma unroll
  for (int m = 0; m < 8; ++m) {
    const unsigned s = s0 + 256u * m;
    const unsigned sc = (s < NG4) ? s : (NG4 - 1u);
    const vf4 pA = ld_nt(pwp + sc);                      // pw: pure stream
    const vf4 pB = ld_nt(pwp + sc + 1);
    // hebb update on ALIGNED groups (a group never crosses a row: 1024/row),
    // then shifted for the aligned store.
    const vf4 hA = hebbp[sc];                            // L2/L3-warm from K1
    const vf4 hB = hebbp[sc + 1];
    const unsigned rA = sc >> 10, rB = (sc + 1) >> 10;
    const unsigned cA = (sc & 1023u) * 4u, cB = ((sc + 1) & 1023u) * 4u;
    const float fA = e * hidden[rA], fB = e * hidden[rB];
    vf4 oA, oB;
#pragma unroll
    for (int c = 0; c < 4; ++c) {
      oA[c] = fmaf(om, hA[c], fA * hactiv[cA + c]);
      oB[c] = fmaf(om, hB[c], fB * hactiv[cB + c]);
    }
    if (s < NG4) {
      st_nt(opw + s, sh3(pA, pB));
      st_nt(oheb + s, sh3(oA, oB));
    }
  }
}

extern "C" void kernel_launch(void* const* d_in, const int* in_sizes, int n_in,
                              void* d_out, int out_size, void* d_ws, size_t ws_size,
                              hipStream_t stream) {
  const float* inputs = (const float*)d_in[0];
  const float* hidden = (const float*)d_in[1];
  const float* hebb   = (const float*)d_in[2];
  const float* et     = (const float*)d_in[3];
  const float* pw     = (const float*)d_in[4];
  const float* i2h_w  = (const float*)d_in[5];
  const float* i2h_b  = (const float*)d_in[6];
  const float* w      = (const float*)d_in[7];
  const float* alpha  = (const float*)d_in[8];
  const float* eta    = (const float*)d_in[9];
  const float* h2o_w  = (const float*)d_in[10];
  const float* h2o_b  = (const float*)d_in[11];
  const float* h2v_w  = (const float*)d_in[12];
  const float* h2v_b  = (const float*)d_in[13];

  float* out = (float*)d_out;
  float* out_heads  = out;               // activout[4] + valueout[1]
  float* out_hactiv = out + 5;           // [HS]      (float offset 5)
  float* out_hebb   = out + 5 + HS;      // [HS*HS]   (float offset 4101 == 1 mod 4)
  float* out_et     = out_hebb + NSQ;    //           (== 1 mod 4)
  float* out_pw     = out_et + NSQ;      //           (== 1 mod 4)

  // Partial scratch: 512*4096 floats = 8 MB. Prefer d_ws; fallback is an
  // aligned slice of the hebb output region (read by finalize_k before
  // hebb_pw_heads_k overwrites it — stream-ordered, safe).
  const size_t need = (size_t)ROW_CHUNKS * HS * sizeof(float);
  float* partial = (ws_size >= need) ? (float*)d_ws
                                     : (out_hebb + 3 /* 16B-aligned */);

  hipLaunchKernelGGL(matvec_et_k, dim3(4, ROW_CHUNKS), dim3(256), 0, stream,
                     hidden, w, alpha, hebb, et, out_et + 3, partial);
  hipLaunchKernelGGL(finalize_k, dim3(HS / 64), dim3(256), 0, stream,
                     partial, inputs, i2h_w, i2h_b, out_hactiv);
  hipLaunchKernelGGL(hebb_pw_heads_k, dim3(2054), dim3(256), 0, stream,
                     hebb, hidden, out_hactiv, eta, pw, et,
                     out_hebb, out_et, out_pw,
                     h2o_w, h2o_b, h2v_w, h2v_b, out_heads);
}